// Round 4
// baseline (451.216 us; speedup 1.0000x reference)
//
#include <hip/hip_runtime.h>
#include <hip/hip_bf16.h>
#include <stdint.h>

#define DIMM 2048
#define HIDD 1024
#define NEXP 8
#define TOPK 2
#define NTOK 2048
#define CAP_E 1024
#define SH_BASE (NEXP * CAP_E)        // 8192
#define NROW (SH_BASE + NTOK)         // 10240

typedef __bf16 bf16_t;
typedef __bf16 bf16x4 __attribute__((ext_vector_type(4)));
typedef __bf16 bf16x8 __attribute__((ext_vector_type(8)));
typedef float f32x4 __attribute__((ext_vector_type(4)));

__device__ __forceinline__ void gl2lds16(const bf16_t* g, bf16_t* l) {
    __builtin_amdgcn_global_load_lds(
        (const __attribute__((address_space(1))) void*)g,
        (__attribute__((address_space(3))) void*)l, 16, 0, 0);
}

// ---------------- router: sigmoid(x @ gw^T), top-2 with bias ----------------
__global__ __launch_bounds__(256) void router_k(const float* __restrict__ x,
                                                const float* __restrict__ gw,
                                                const float* __restrict__ bias,
                                                int* __restrict__ sel,
                                                float* __restrict__ topsc) {
    int t = blockIdx.x;
    int tid = threadIdx.x;
    const float* xr = x + (long)t * DIMM;
    double acc[NEXP];
#pragma unroll
    for (int e = 0; e < NEXP; ++e) acc[e] = 0.0;
    for (int d = tid; d < DIMM; d += 256) {
        double xv = (double)xr[d];
#pragma unroll
        for (int e = 0; e < NEXP; ++e) acc[e] += xv * (double)gw[e * DIMM + d];
    }
#pragma unroll
    for (int off = 32; off >= 1; off >>= 1)
#pragma unroll
        for (int e = 0; e < NEXP; ++e) acc[e] += __shfl_down(acc[e], off, 64);
    __shared__ double red[4][NEXP];
    int lane = tid & 63, w = tid >> 6;
    if (lane == 0)
#pragma unroll
        for (int e = 0; e < NEXP; ++e) red[w][e] = acc[e];
    __syncthreads();
    if (tid == 0) {
        double sc[NEXP], v[NEXP];
#pragma unroll
        for (int e = 0; e < NEXP; ++e) {
            double s = red[0][e] + red[1][e] + red[2][e] + red[3][e];
            sc[e] = 1.0 / (1.0 + exp(-s));
            v[e] = sc[e] + (double)bias[e];
        }
        int b0 = 0;
        for (int e = 1; e < NEXP; ++e) if (v[e] > v[b0]) b0 = e;
        int b1 = -1;
        for (int e = 0; e < NEXP; ++e)
            if (e != b0 && (b1 < 0 || v[e] > v[b1])) b1 = e;
        sel[t * 2] = b0; sel[t * 2 + 1] = b1;
        topsc[t * 2] = (float)sc[b0]; topsc[t * 2 + 1] = (float)sc[b1];
    }
}

// ------- stable counting sort into per-expert segments + inverse perm -------
__global__ __launch_bounds__(256) void sort_k(const int* __restrict__ sel,
                                              const float* __restrict__ topsc,
                                              int* __restrict__ tok_s,
                                              float* __restrict__ sc_s,
                                              int* __restrict__ counts,
                                              int* __restrict__ pos) {
    __shared__ int se[NTOK * TOPK];
    int tid = threadIdx.x;
    for (int i = tid; i < NTOK * TOPK; i += 256) se[i] = sel[i];
    __syncthreads();
    int wv = tid >> 6, lane = tid & 63;
    unsigned long long lower = (1ull << lane) - 1ull;
    for (int ei = 0; ei < 2; ++ei) {
        int e = wv * 2 + ei;
        int base = e * CAP_E;
        int off = 0;
        for (int c = 0; c < (NTOK * TOPK) / 64; ++c) {
            int slot = c * 64 + lane;
            bool m = (se[slot] == e);
            unsigned long long bal = __ballot(m);
            if (m) {
                int rank = off + __popcll(bal & lower);
                if (rank < CAP_E) {
                    tok_s[base + rank] = slot >> 1;  // TOPK = 2
                    sc_s[base + rank] = topsc[slot];
                    pos[slot] = base + rank;
                } else {
                    pos[slot] = -1;
                }
            }
            off += __popcll(bal);
        }
        int cnt = min(off, CAP_E);
        if (lane == 0) counts[e] = cnt;
        int padded = min((cnt + 127) & ~127, CAP_E);
        for (int r = cnt + lane; r < padded; r += 64) tok_s[base + r] = -1;
    }
}

// ---------- gather + scale -> rin bf16 (routed segs + shared block) ----------
__global__ __launch_bounds__(256) void build_rin(const float* __restrict__ x,
                                                 const int* __restrict__ tok_s,
                                                 const float* __restrict__ sc_s,
                                                 const int* __restrict__ counts,
                                                 bf16_t* __restrict__ rin) {
    int row = blockIdx.x;
    int tok; float sc = 1.0f;
    if (row >= SH_BASE) {
        tok = row - SH_BASE;
    } else {
        int e = row >> 10, r = row & (CAP_E - 1);
        int cnt = min(counts[e], CAP_E);
        int padded = min((cnt + 127) & ~127, CAP_E);
        if (r >= padded) return;
        if (r < cnt) { tok = tok_s[row]; sc = sc_s[row]; }
        else tok = -1;
    }
    int d0 = threadIdx.x * 8;
    bf16x8 o;
    if (tok >= 0) {
        const float* src = x + (long)tok * DIMM + d0;
        float4 a = *(const float4*)src;
        float4 b = *(const float4*)(src + 4);
        o[0] = (bf16_t)(a.x * sc); o[1] = (bf16_t)(a.y * sc);
        o[2] = (bf16_t)(a.z * sc); o[3] = (bf16_t)(a.w * sc);
        o[4] = (bf16_t)(b.x * sc); o[5] = (bf16_t)(b.y * sc);
        o[6] = (bf16_t)(b.z * sc); o[7] = (bf16_t)(b.w * sc);
    } else {
#pragma unroll
        for (int i = 0; i < 8; ++i) o[i] = (bf16_t)0.0f;
    }
    *(bf16x8*)(rin + (long)row * DIMM + d0) = o;
}

// ------------- pipelined grouped GEMM, BK=32, dbuf LDS = 32 KB -------------
// PHASE 1: K=2048, B-tile row r -> (r>>4)&1 ? w3 : w1; SiLU fused epilogue.
// PHASE 2: K=1024, B = w2[g]; plain fp32 store to C2 (sorted-row space).

#define STAGE_A(kt, buf) do { \
    gl2lds16(arow0 + (kt) * 32, &lA[buf][tid * 8]); \
    gl2lds16(arow1 + (kt) * 32, &lA[buf][(256 + tid) * 8]); \
} while (0)

#define LOAD_B(kt, s) do { \
    u##s[0] = *(const float4*)(brow0 + (kt) * 32); \
    v##s[0] = *(const float4*)(brow0 + (kt) * 32 + 4); \
    u##s[1] = *(const float4*)(brow1 + (kt) * 32); \
    v##s[1] = *(const float4*)(brow1 + (kt) * 32 + 4); \
} while (0)

#define WRITE_B(s, buf) do { \
    _Pragma("unroll") \
    for (int i_ = 0; i_ < 2; ++i_) { \
        bf16x8 o_ = {(bf16_t)u##s[i_].x, (bf16_t)u##s[i_].y, \
                     (bf16_t)u##s[i_].z, (bf16_t)u##s[i_].w, \
                     (bf16_t)v##s[i_].x, (bf16_t)v##s[i_].y, \
                     (bf16_t)v##s[i_].z, (bf16_t)v##s[i_].w}; \
        *(bf16x8*)&lB[buf][bslot[i_] * 8] = o_; \
    } \
} while (0)

#define MFMA_TILE(buf) do { \
    bf16x8 af_[4], bg_[4]; \
    _Pragma("unroll") \
    for (int mi_ = 0; mi_ < 4; ++mi_) { \
        int row_ = wm + mi_ * 16 + l16; \
        af_[mi_] = *(const bf16x8*)&lA[buf][(row_ * 4 + (quad ^ (row_ & 3))) * 8]; \
    } \
    _Pragma("unroll") \
    for (int ni_ = 0; ni_ < 4; ++ni_) { \
        int row_ = wn + ni_ * 16 + l16; \
        bg_[ni_] = *(const bf16x8*)&lB[buf][(row_ * 4 + (quad ^ (row_ & 3))) * 8]; \
    } \
    _Pragma("unroll") \
    for (int mi_ = 0; mi_ < 4; ++mi_) \
        _Pragma("unroll") \
        for (int ni_ = 0; ni_ < 4; ++ni_) \
            acc[mi_][ni_] = __builtin_amdgcn_mfma_f32_16x16x32_bf16( \
                af_[mi_], bg_[ni_], acc[mi_][ni_], 0, 0, 0); \
} while (0)

template <int PHASE>
__global__ __launch_bounds__(256, 3) void gemm_moe(
    const bf16_t* __restrict__ A0,
    const float* __restrict__ W1, const float* __restrict__ W3,
    const float* __restrict__ SW1, const float* __restrict__ SW3,
    bf16_t* __restrict__ hOut, float* __restrict__ C2,
    const int* __restrict__ counts) {
    constexpr int K = (PHASE == 1) ? 2048 : 1024;
    constexpr int KT = K / 32;
    int g = blockIdx.z;
    int base = (g < 8) ? g * CAP_E : SH_BASE;
    int M = NTOK;
    if (g < 8) {
        int c = min(counts[g], CAP_E);
        M = min((c + 127) & ~127, CAP_E);
    }
    int m0 = blockIdx.y * 128;
    if (m0 >= M) return;
    const bf16_t* A = A0 + (long)base * K;

    __shared__ bf16_t lA[2][128 * 32];
    __shared__ bf16_t lB[2][128 * 32];

    int tid = threadIdx.x;
    int lane = tid & 63, wv = tid >> 6;
    int quad = lane >> 4, l16 = lane & 15;
    int wm = (wv & 1) * 64, wn = (wv >> 1) * 64;
    int j4 = tid & 3;           // chunk index (8 elems of 32-col tile)
    int r4 = tid >> 2;          // row 0..63

    // A staging source pointers (rows r4 and r4+64), swizzled chunk
    const bf16_t* arow0 = A + (long)(m0 + r4) * K + ((j4 ^ (r4 & 3)) << 3);
    const bf16_t* arow1 = A + (long)(m0 + 64 + r4) * K + ((j4 ^ ((64 + r4) & 3)) << 3);

    // B staging: fp32 row pointers + swizzled LDS slots (rows r4, r4+64)
    const float* brow0;
    const float* brow1;
    int bslot[2];
    {
        int rr[2] = {r4, 64 + r4};
        const float* bp[2];
#pragma unroll
        for (int i = 0; i < 2; ++i) {
            int r = rr[i];
            const float* p;
            if (PHASE == 1) {
                int colw = (blockIdx.x << 6) + ((r >> 5) << 4) + (r & 15);
                int type = (r >> 4) & 1;
                if (g < 8) p = (type ? W3 : W1) + ((long)g << 21) + (long)colw * DIMM;
                else       p = (type ? SW3 : SW1) + (long)colw * DIMM;
            } else {
                int n = (blockIdx.x << 7) + r;
                p = ((g < 8) ? W1 + ((long)g << 21) : SW1) + (long)n * HIDD;
            }
            bp[i] = p + (j4 << 3);
            bslot[i] = r * 4 + (j4 ^ (r & 3));
        }
        brow0 = bp[0]; brow1 = bp[1];
    }

    f32x4 acc[4][4];
#pragma unroll
    for (int i = 0; i < 4; ++i)
#pragma unroll
        for (int j = 0; j < 4; ++j) acc[i][j] = (f32x4){0.f, 0.f, 0.f, 0.f};

    float4 u0[2], v0[2], u1[2], v1[2];
    // prologue
    STAGE_A(0, 0);
    LOAD_B(0, 0);
    WRITE_B(0, 0);
    LOAD_B(1, 1);
    __syncthreads();

    for (int kt = 0; kt < KT; kt += 2) {
        // even sub-iter: consume buf0 (tile kt)
        STAGE_A(kt + 1, 1);
        if (kt + 2 < KT) LOAD_B(kt + 2, 0);
        MFMA_TILE(0);
        WRITE_B(1, 1);
        __syncthreads();
        // odd sub-iter: consume buf1 (tile kt+1)
        if (kt + 2 < KT) {
            STAGE_A(kt + 2, 0);
            if (kt + 3 < KT) LOAD_B(kt + 3, 1);
        }
        MFMA_TILE(1);
        if (kt + 2 < KT) WRITE_B(0, 0);
        __syncthreads();
    }

    if (PHASE == 1) {
        // acc[mi][ni]: ni even = gate, ni odd = up
#pragma unroll
        for (int mi = 0; mi < 4; ++mi)
#pragma unroll
            for (int r = 0; r < 4; ++r) {
                long row = base + m0 + wm + mi * 16 + quad * 4 + r;
#pragma unroll
                for (int j = 0; j < 2; ++j) {
                    float gt = acc[mi][2 * j][r];
                    float up = acc[mi][2 * j + 1][r];
                    float s = gt / (1.f + __expf(-gt));
                    int col = (blockIdx.x << 6) + ((wn >> 5) + j) * 16 + l16;
                    hOut[row * HIDD + col] = (bf16_t)(s * up);
                }
            }
    } else {
#pragma unroll
        for (int mi = 0; mi < 4; ++mi)
#pragma unroll
            for (int r = 0; r < 4; ++r) {
                long row = base + m0 + wm + mi * 16 + quad * 4 + r;
#pragma unroll
                for (int ni = 0; ni < 4; ++ni) {
                    int col = (blockIdx.x << 7) + wn + ni * 16 + l16;
                    C2[row * DIMM + col] = acc[mi][ni][r];
                }
            }
    }
}

// ---------------- combine: out[t] = shared + slot0 + slot1 ----------------
__global__ __launch_bounds__(256) void combine_k(const float* __restrict__ C2,
                                                 const int* __restrict__ pos,
                                                 float* __restrict__ out) {
    int t = blockIdx.x;
    int c = threadIdx.x * 8;
    int p0 = pos[t * 2], p1 = pos[t * 2 + 1];
    const float* sh = C2 + (long)(SH_BASE + t) * DIMM + c;
    float4 a = *(const float4*)sh;
    float4 b = *(const float4*)(sh + 4);
    if (p0 >= 0) {
        const float* q = C2 + (long)p0 * DIMM + c;
        float4 qa = *(const float4*)q, qb = *(const float4*)(q + 4);
        a.x += qa.x; a.y += qa.y; a.z += qa.z; a.w += qa.w;
        b.x += qb.x; b.y += qb.y; b.z += qb.z; b.w += qb.w;
    }
    if (p1 >= 0) {
        const float* q = C2 + (long)p1 * DIMM + c;
        float4 qa = *(const float4*)q, qb = *(const float4*)(q + 4);
        a.x += qa.x; a.y += qa.y; a.z += qa.z; a.w += qa.w;
        b.x += qb.x; b.y += qb.y; b.z += qb.z; b.w += qb.w;
    }
    float* op = out + (long)t * DIMM + c;
    *(float4*)op = a;
    *(float4*)(op + 4) = b;
}

extern "C" void kernel_launch(void* const* d_in, const int* in_sizes, int n_in,
                              void* d_out, int out_size, void* d_ws, size_t ws_size,
                              hipStream_t stream) {
    const float* x    = (const float*)d_in[0];
    const float* bias = (const float*)d_in[1];
    const float* gw   = (const float*)d_in[2];
    const float* w1   = (const float*)d_in[3];
    const float* w2   = (const float*)d_in[4];
    const float* w3   = (const float*)d_in[5];
    const float* sw1  = (const float*)d_in[6];
    const float* sw2  = (const float*)d_in[7];
    const float* sw3  = (const float*)d_in[8];
    float* out = (float*)d_out;

    char* p = (char*)d_ws;
    auto alloc = [&](size_t bytes) {
        char* r = p;
        p += (bytes + 255) & ~(size_t)255;
        return r;
    };
    bf16_t* rin   = (bf16_t*)alloc((size_t)NROW * DIMM * 2);   // 40 MB
    bf16_t* hB    = (bf16_t*)alloc((size_t)NROW * HIDD * 2);   // 20 MB
    float*  C2    = (float*)alloc((size_t)NROW * DIMM * 4);    // 80 MB
    int*   sel    = (int*)alloc(NTOK * TOPK * 4);
    float* topsc  = (float*)alloc(NTOK * TOPK * 4);
    int*   tok_s  = (int*)alloc(SH_BASE * 4);
    float* sc_s   = (float*)alloc(SH_BASE * 4);
    int*   pos    = (int*)alloc(NTOK * TOPK * 4);
    int*   counts = (int*)alloc(256);

    router_k<<<NTOK, 256, 0, stream>>>(x, gw, bias, sel, topsc);
    sort_k<<<1, 256, 0, stream>>>(sel, topsc, tok_s, sc_s, counts, pos);
    build_rin<<<NROW, 256, 0, stream>>>(x, tok_s, sc_s, counts, rin);

    // GEMM1 + fused SiLU: hB[g] = silu(A@w1^T) * (A@w3^T)   (9 groups)
    gemm_moe<1><<<dim3(16, 16, 9), 256, 0, stream>>>(
        rin, w1, w3, sw1, sw3, hB, nullptr, counts);

    // GEMM2: C2[g] = hB[g] @ w2[g]^T   (9 groups, plain fp32 store)
    gemm_moe<2><<<dim3(16, 16, 9), 256, 0, stream>>>(
        hB, w2, nullptr, sw2, nullptr, nullptr, C2, counts);

    combine_k<<<NTOK, 256, 0, stream>>>(C2, pos, out);
}